// Round 13
// baseline (3300.986 us; speedup 1.0000x reference)
//
#include <hip/hip_runtime.h>
#include <math.h>

#define NEG_INF (-1e9f)
#define WSYNC() asm volatile("s_waitcnt lgkmcnt(0)" ::: "memory")
#define SW(n) ((((n) ^ ((n) >> 3))) & 7)

// ---------------------------------------------------------------------------
// DPP cross-lane helpers (bit-identical to xor-butterflies; R9/R10 notes)
// ---------------------------------------------------------------------------
template <int CTRL>
__device__ __forceinline__ float dppf(float x, float oldv) {
  return __int_as_float(__builtin_amdgcn_update_dpp(
      __float_as_int(oldv), __float_as_int(x), CTRL, 0xF, 0xF, false));
}
template <int CTRL>
__device__ __forceinline__ int dppi(int x, int oldv) {
  return __builtin_amdgcn_update_dpp(oldv, x, CTRL, 0xF, 0xF, false);
}
__device__ __forceinline__ float rdlane63f(float x) {
  return __int_as_float(__builtin_amdgcn_readlane(__float_as_int(x), 63));
}
__device__ __forceinline__ float wred_sum(float x) {
  x += dppf<0xB1>(x, 0.f);
  x += dppf<0x4E>(x, 0.f);
  x += dppf<0x141>(x, 0.f);
  x += dppf<0x140>(x, 0.f);
  x += dppf<0x142>(x, 0.f);
  x += dppf<0x143>(x, 0.f);
  return rdlane63f(x);
}
__device__ __forceinline__ float fast_tanh(float x) {
  float t = __expf(-2.0f * fabsf(x));
  float r = (1.0f - t) / (1.0f + t);
  return copysignf(r, x);
}

// ---------------------------------------------------------------------------
// pre_kernel: ws[0..16383] = Wc (1/sqrt(128) folded); ws[16384..16511] = qp
// ---------------------------------------------------------------------------
__global__ __launch_bounds__(128) void pre_kernel(
    const float* __restrict__ W_node, const float* __restrict__ W_out,
    const float* __restrict__ W_step, const float* __restrict__ W_ph,
    float* __restrict__ ws) {
  const int bi = blockIdx.x;
  const int tid = threadIdx.x;
  if (bi < 64) {
    __shared__ float woT[64][133];
    float acc0 = 0.f, acc1 = 0.f;
    const int e0 = bi * 2, e1 = e0 + 1;
    for (int ch = 0; ch < 2; ++ch) {
      const int j0 = ch * 64;
      for (int it = 0; it < 64; ++it) {
        int idx = tid + it * 128;
        int jj = idx & 63, ds = idx >> 6;
        woT[jj][ds] = W_out[ds * 128 + j0 + jj];
      }
      __syncthreads();
      for (int jj = 0; jj < 64; ++jj) {
        int j = j0 + jj;
        float a0 = W_node[e0 * 384 + 256 + j];
        float a1 = W_node[e1 * 384 + 256 + j];
        float bb = woT[jj][tid];
        acc0 = fmaf(a0, bb, acc0);
        acc1 = fmaf(a1, bb, acc1);
      }
      __syncthreads();
    }
    const float rs = 0.08838834764831845f;  // 1/sqrt(128)
    ws[e0 * 128 + tid] = acc0 * rs;
    ws[e1 * 128 + tid] = acc1 * rs;
  } else {
    float acc = 0.f;
    for (int i = 0; i < 256; ++i) acc = fmaf(W_ph[i], W_step[i * 128 + tid], acc);
    ws[16384 + tid] = acc;
  }
}

// ---------------------------------------------------------------------------
// ecomp_kernel: Eg[b][n][d] = 0.25 * sum_e emb[b][n][e] * W_step[128+e][d]
// ---------------------------------------------------------------------------
__global__ __launch_bounds__(512) void ecomp_kernel(
    const float* __restrict__ emb, const float* __restrict__ W_step,
    float* __restrict__ Eg) {
  const int b = blockIdx.x;
  const int tid = threadIdx.x;
  const int c = tid & 31;
  const int g = tid >> 5;

  __shared__ __align__(16) float semb[100 * 128];
  __shared__ __align__(16) float sW[128 * 128];

  float4* semb4 = (float4*)semb;
  float4* sW4 = (float4*)sW;
  const float4* embB4 = (const float4*)(emb + (size_t)b * 12800);
  const float4* Wb4 = (const float4*)(W_step + 128 * 128);

  for (int it = 0; it < 7; ++it) {
    int qi = tid + it * 512;
    if (qi < 3200) {
      int n = qi >> 5, cc = qi & 31;
      semb4[n * 32 + (cc ^ SW(n))] = embB4[qi];
    }
  }
  for (int it = 0; it < 8; ++it) sW4[tid + it * 512] = Wb4[tid + it * 512];
  __syncthreads();

  float4 acc[7];
#pragma unroll
  for (int k = 0; k < 7; ++k) acc[k] = make_float4(0.f, 0.f, 0.f, 0.f);
#pragma unroll 2
  for (int e4 = 0; e4 < 32; ++e4) {
    float4 em[7];
#pragma unroll
    for (int k = 0; k < 7; ++k) {
      int n = g + 16 * k; n = (n < 100) ? n : 99;
      em[k] = semb4[n * 32 + (e4 ^ SW(n))];
    }
#pragma unroll
    for (int eo = 0; eo < 4; ++eo) {
      float4 w4 = sW4[(e4 * 4 + eo) * 32 + c];
#pragma unroll
      for (int k = 0; k < 7; ++k) {
        const float ev = (eo == 0) ? em[k].x : (eo == 1) ? em[k].y
                       : (eo == 2) ? em[k].z : em[k].w;
        acc[k].x = fmaf(ev, w4.x, acc[k].x);
        acc[k].y = fmaf(ev, w4.y, acc[k].y);
        acc[k].z = fmaf(ev, w4.z, acc[k].z);
        acc[k].w = fmaf(ev, w4.w, acc[k].w);
      }
    }
  }
  float4* Eg4 = (float4*)Eg;
#pragma unroll
  for (int k = 0; k < 7; ++k) {
    int n = g + 16 * k;
    if (n < 100)
      Eg4[((size_t)b * 100 + n) * 32 + c] =
          make_float4(0.25f * acc[k].x, 0.25f * acc[k].y,
                      0.25f * acc[k].z, 0.25f * acc[k].w);
  }
}

// ---------------------------------------------------------------------------
// lcomp_kernel: Lk[b][n][d] = sum_e emb[b][n][e] * Wc[e][d]
// ---------------------------------------------------------------------------
__global__ __launch_bounds__(512) void lcomp_kernel(
    const float* __restrict__ emb, const float* __restrict__ Wc,
    float* __restrict__ Lk) {
  const int b = blockIdx.x;
  const int tid = threadIdx.x;
  const int c = tid & 31;
  const int g = tid >> 5;

  __shared__ __align__(16) float semb[100 * 128];
  __shared__ __align__(16) float sW[128 * 128];

  float4* semb4 = (float4*)semb;
  float4* sW4 = (float4*)sW;
  const float4* embB4 = (const float4*)(emb + (size_t)b * 12800);
  const float4* Wb4 = (const float4*)Wc;

  for (int it = 0; it < 7; ++it) {
    int qi = tid + it * 512;
    if (qi < 3200) {
      int n = qi >> 5, cc = qi & 31;
      semb4[n * 32 + (cc ^ SW(n))] = embB4[qi];
    }
  }
  for (int it = 0; it < 8; ++it) sW4[tid + it * 512] = Wb4[tid + it * 512];
  __syncthreads();

  float4 acc[7];
#pragma unroll
  for (int k = 0; k < 7; ++k) acc[k] = make_float4(0.f, 0.f, 0.f, 0.f);
#pragma unroll 2
  for (int e4 = 0; e4 < 32; ++e4) {
    float4 em[7];
#pragma unroll
    for (int k = 0; k < 7; ++k) {
      int n = g + 16 * k; n = (n < 100) ? n : 99;
      em[k] = semb4[n * 32 + (e4 ^ SW(n))];
    }
#pragma unroll
    for (int eo = 0; eo < 4; ++eo) {
      float4 w4 = sW4[(e4 * 4 + eo) * 32 + c];
#pragma unroll
      for (int k = 0; k < 7; ++k) {
        const float ev = (eo == 0) ? em[k].x : (eo == 1) ? em[k].y
                       : (eo == 2) ? em[k].z : em[k].w;
        acc[k].x = fmaf(ev, w4.x, acc[k].x);
        acc[k].y = fmaf(ev, w4.y, acc[k].y);
        acc[k].z = fmaf(ev, w4.z, acc[k].z);
        acc[k].w = fmaf(ev, w4.w, acc[k].w);
      }
    }
  }
  float4* Lk4 = (float4*)Lk;
#pragma unroll
  for (int k = 0; k < 7; ++k) {
    int n = g + 16 * k;
    if (n < 100) Lk4[((size_t)b * 100 + n) * 32 + c] = acc[k];
  }
}

// ---------------------------------------------------------------------------
// decode_u: DUAL batch rows per 512-thread block (grid 1024). 1 WG/CU is a
// hard pin (proven R2..R11), so the second independent dependence chain goes
// INSIDE the block: each thread serves (h,l) for rows A and B, phases
// interleaved; one barrier/step serves both. Register-persistent per row:
// gvt[25] only. gk in LDS (gkT, transposed conflict-free, step-invariant
// loads issued early); lk' from global Lkg (R11-proven); E from global Eg
// (R8-proven); ctx+F via LDS broadcast. LDS 130,048 B.
// ---------------------------------------------------------------------------
__global__ __launch_bounds__(512) void decode_u(
    const float* __restrict__ emb,      // [2048][100][128]
    const float* __restrict__ W_node,   // [128][384]
    const float* __restrict__ W_fixed,  // [128][128]
    const float* __restrict__ W_step,   // [256][128]
    const float* __restrict__ ws,       // Wc + qp
    const float* __restrict__ Eg,       // 0.25*E
    const float* __restrict__ Lkg,      // lk'
    float* __restrict__ out_logp,       // [2048][100][100]
    float* __restrict__ out_pi) {       // [2048][100]
  const int tid = threadIdx.x;
  const int h = tid >> 6;
  const int l = tid & 63;
  const int dp = l >> 2;
  const int qg = l & 3;
  const bool act = (l < 50);
  const int r0 = act ? l : 0;
  const int r1 = act ? l + 50 : 0;
  const int qq0 = (l < 25) ? 0 : 1;
  const int ii0 = l - qq0 * 25;
  const int bA = blockIdx.x * 2;
  const int bB = bA + 1;

  __shared__ __align__(16) float gkT[2][12800];   // 102,400 B
  __shared__ __align__(16) float pool[2][3200];   // 25,600 B
  __shared__ float smean[2][128];
  __shared__ __align__(16) float sbase[2][8][16];

  // ======================= INIT (row-sequential) ==========================
  float gvtA[25], gvtB[25];
#define INIT_ROW(RR, BV, GVT)                                                \
  {                                                                          \
    const float* embB = emb + (size_t)(BV)*12800;                            \
    const float4* embB4 = (const float4*)embB;                               \
    {                                                                        \
      int d = tid & 127, q2 = tid >> 7;                                      \
      float p = 0.f;                                                         \
      for (int n = q2 * 25; n < q2 * 25 + 25; ++n) p += embB[n * 128 + d];   \
      pool[RR][q2 * 128 + d] = p;                                            \
    }                                                                        \
    __syncthreads();                                                         \
    if (tid < 128)                                                           \
      smean[RR][tid] = (pool[RR][tid] + pool[RR][128 + tid] +                \
                        pool[RR][256 + tid] + pool[RR][384 + tid]) * 0.01f;  \
    __syncthreads();                                                         \
    {                                                                        \
      float a = 0.f;                                                         \
      for (int i = 0; i < 32; ++i) {                                         \
        int e = qg * 32 + i;                                                 \
        a = fmaf(smean[RR][e], W_fixed[e * 128 + h * 16 + dp], a);           \
      }                                                                      \
      a += dppf<0xB1>(a, 0.f);                                               \
      a += dppf<0x4E>(a, 0.f);                                               \
      if ((l & 3) == 0) sbase[RR][h][l >> 2] = 0.25f * a;                    \
    }                                                                        \
    {                                                                        \
      float gv0[16], gv1[16];                                                \
      _Pragma("unroll")                                                      \
      for (int j = 0; j < 16; ++j) gv0[j] = gv1[j] = 0.f;                    \
      _Pragma("unroll 2")                                                    \
      for (int e4 = 0; e4 < 32; ++e4) {                                      \
        float4 a0 = embB4[r0 * 32 + e4];                                     \
        float4 a1 = embB4[r1 * 32 + e4];                                     \
        float em0[4] = {a0.x, a0.y, a0.z, a0.w};                             \
        float em1[4] = {a1.x, a1.y, a1.z, a1.w};                             \
        _Pragma("unroll")                                                    \
        for (int eo = 0; eo < 4; ++eo) {                                     \
          const int e = e4 * 4 + eo;                                         \
          const float ev0 = em0[eo], ev1 = em1[eo];                          \
          const float* wv = &W_node[e * 384 + 128 + h * 16];                 \
          _Pragma("unroll")                                                  \
          for (int j = 0; j < 16; ++j) {                                     \
            float wvj = wv[j];                                               \
            gv0[j] = fmaf(ev0, wvj, gv0[j]);                                 \
            gv1[j] = fmaf(ev1, wvj, gv1[j]);                                 \
          }                                                                  \
        }                                                                    \
      }                                                                      \
      float* gvtmp = pool[RR];                                               \
      __syncthreads(); /* mean scratch done everywhere */                    \
      _Pragma("unroll 1")                                                    \
      for (int pass = 0; pass < 4; ++pass) {                                 \
        WSYNC();                                                             \
        if (act) {                                                           \
          if (qq0 == pass) {                                                 \
            float4* w = (float4*)(gvtmp + (h * 25 + ii0) * 16);              \
            _Pragma("unroll")                                                \
            for (int jj = 0; jj < 4; ++jj)                                   \
              w[jj] = make_float4(gv0[jj * 4], gv0[jj * 4 + 1],              \
                                  gv0[jj * 4 + 2], gv0[jj * 4 + 3]);         \
          }                                                                  \
          if (qq0 + 2 == pass) {                                             \
            float4* w = (float4*)(gvtmp + (h * 25 + ii0) * 16);              \
            _Pragma("unroll")                                                \
            for (int jj = 0; jj < 4; ++jj)                                   \
              w[jj] = make_float4(gv1[jj * 4], gv1[jj * 4 + 1],              \
                                  gv1[jj * 4 + 2], gv1[jj * 4 + 3]);         \
          }                                                                  \
        }                                                                    \
        WSYNC();                                                             \
        if (qg == pass) {                                                    \
          _Pragma("unroll")                                                  \
          for (int i = 0; i < 25; ++i) GVT[i] = gvtmp[(h * 25 + i) * 16 + dp]; \
        }                                                                    \
      }                                                                      \
    }                                                                        \
    __syncthreads(); /* pool handoff to loop layout */                       \
    if (l == 0) {                                                            \
      _Pragma("unroll")                                                      \
      for (int j = 0; j < 16; ++j)                                           \
        pool[RR][2624 + h * 16 + j] =                                        \
            sbase[RR][h][j] + 0.25f * ws[16384 + h * 16 + j];                \
    }                                                                        \
    {                                                                        \
      float gk0[16], gk1[16];                                                \
      _Pragma("unroll")                                                      \
      for (int j = 0; j < 16; ++j) gk0[j] = gk1[j] = 0.f;                    \
      _Pragma("unroll 2")                                                    \
      for (int e4 = 0; e4 < 32; ++e4) {                                      \
        float4 a0 = embB4[r0 * 32 + e4];                                     \
        float4 a1 = embB4[r1 * 32 + e4];                                     \
        float em0[4] = {a0.x, a0.y, a0.z, a0.w};                             \
        float em1[4] = {a1.x, a1.y, a1.z, a1.w};                             \
        _Pragma("unroll")                                                    \
        for (int eo = 0; eo < 4; ++eo) {                                     \
          const int e = e4 * 4 + eo;                                         \
          const float ev0 = em0[eo], ev1 = em1[eo];                          \
          const float* wk = &W_node[e * 384 + h * 16];                       \
          _Pragma("unroll")                                                  \
          for (int j = 0; j < 16; ++j) {                                     \
            float wkj = wk[j];                                               \
            gk0[j] = fmaf(ev0, wkj, gk0[j]);                                 \
            gk1[j] = fmaf(ev1, wkj, gk1[j]);                                 \
          }                                                                  \
        }                                                                    \
      }                                                                      \
      if (act) {                                                             \
        _Pragma("unroll")                                                    \
        for (int j = 0; j < 16; ++j) {                                       \
          gkT[RR][(h * 16 + j) * 100 + r0] = gk0[j];                         \
          gkT[RR][(h * 16 + j) * 100 + r1] = gk1[j];                         \
        }                                                                    \
      }                                                                      \
    }                                                                        \
  }

  INIT_ROW(0, bA, gvtA)
  INIT_ROW(1, bB, gvtB)
#undef INIT_ROW
  __syncthreads();  // gkT / sqp / sbase visible block-wide

  // ======================= decode loop ====================================
  bool m0A = false, m1A = false, m0B = false, m1B = false;
  int lastA = 0, lastB = 0;
  int par = 0;
  const size_t lpA = (size_t)bA * 10000;
  const size_t lpB = (size_t)bB * 10000;

  // per-row compat: query row formed from sbase+Eg (or sqp at t==0),
  // gk from gkT (step-invariant addresses).
#define COMPAT(RR, BV, LASTV, M0, M1, V0, V1)                                \
  {                                                                          \
    float q[16];                                                             \
    if (t == 0) {                                                            \
      const float4* qp = (const float4*)(pool[RR] + 2624 + h * 16);          \
      _Pragma("unroll")                                                      \
      for (int jj = 0; jj < 4; ++jj) {                                       \
        float4 v = qp[jj];                                                   \
        q[4 * jj + 0] = v.x; q[4 * jj + 1] = v.y;                            \
        q[4 * jj + 2] = v.z; q[4 * jj + 3] = v.w;                            \
      }                                                                      \
    } else {                                                                 \
      const float4* egp =                                                    \
          (const float4*)(Eg + ((size_t)(BV)*100 + (LASTV)) * 128 + h * 16); \
      const float4* sb = (const float4*)&sbase[RR][h][0];                    \
      _Pragma("unroll")                                                      \
      for (int jj = 0; jj < 4; ++jj) {                                       \
        float4 g = egp[jj];                                                  \
        float4 c = sb[jj];                                                   \
        q[4 * jj + 0] = c.x + g.x; q[4 * jj + 1] = c.y + g.y;                \
        q[4 * jj + 2] = c.z + g.z; q[4 * jj + 3] = c.w + g.w;                \
      }                                                                      \
    }                                                                        \
    float c0a = 0.f, c0b = 0.f, c1a = 0.f, c1b = 0.f;                        \
    _Pragma("unroll")                                                        \
    for (int j = 0; j < 8; ++j) {                                            \
      float g0 = gkT[RR][(h * 16 + j) * 100 + r0];                           \
      float g1 = gkT[RR][(h * 16 + j) * 100 + r1];                           \
      c0a = fmaf(q[j], g0, c0a);                                             \
      c1a = fmaf(q[j], g1, c1a);                                             \
    }                                                                        \
    _Pragma("unroll")                                                        \
    for (int j = 8; j < 16; ++j) {                                           \
      float g0 = gkT[RR][(h * 16 + j) * 100 + r0];                           \
      float g1 = gkT[RR][(h * 16 + j) * 100 + r1];                           \
      c0b = fmaf(q[j], g0, c0b);                                             \
      c1b = fmaf(q[j], g1, c1b);                                             \
    }                                                                        \
    V0 = (act && !(M0)) ? (c0a + c0b) : NEG_INF;                             \
    V1 = (act && !(M1)) ? (c1a + c1b) : NEG_INF;                             \
  }

#define HEADS_LOGITS(RR, BV, GVT, SV, EV0, EV1)                              \
  {                                                                          \
    float* sattnH = pool[RR] + h * 112;                                      \
    const float* ap = sattnH + qg * 28;                                      \
    float ha = 0.f, hb = 0.f;                                                \
    _Pragma("unroll")                                                        \
    for (int ii = 0; ii < 6; ++ii) {                                         \
      float4 v = ((const float4*)ap)[ii];                                    \
      ha = fmaf(v.x, GVT[4 * ii + 0], ha);                                   \
      hb = fmaf(v.y, GVT[4 * ii + 1], hb);                                   \
      ha = fmaf(v.z, GVT[4 * ii + 2], ha);                                   \
      hb = fmaf(v.w, GVT[4 * ii + 3], hb);                                   \
    }                                                                        \
    ha = fmaf(ap[24], GVT[24], ha);                                          \
    float hacc = ha + hb;                                                    \
    hacc += dppf<0xB1>(hacc, 0.f);                                           \
    hacc += dppf<0x4E>(hacc, 0.f);                                           \
    float hd = hacc / (SV);                                                  \
    float shv[16];                                                           \
    _Pragma("unroll")                                                        \
    for (int j = 0; j < 16; ++j)                                             \
      shv[j] = __int_as_float(                                               \
          __builtin_amdgcn_readlane(__float_as_int(hd), 4 * j));             \
    const float4* lkp0 =                                                     \
        (const float4*)(Lkg + ((size_t)(BV)*100 + r0) * 128 + h * 16);       \
    const float4* lkp1 =                                                     \
        (const float4*)(Lkg + ((size_t)(BV)*100 + r1) * 128 + h * 16);       \
    float4 L0 = lkp0[0], L1 = lkp0[1], L2 = lkp0[2], L3 = lkp0[3];           \
    float4 M0_ = lkp1[0], M1_ = lkp1[1], M2_ = lkp1[2], M3_ = lkp1[3];       \
    float p0a = 0.f, p0b = 0.f, p1a = 0.f, p1b = 0.f;                        \
    p0a = fmaf(shv[0], L0.x, p0a);  p1a = fmaf(shv[0], M0_.x, p1a);          \
    p0a = fmaf(shv[1], L0.y, p0a);  p1a = fmaf(shv[1], M0_.y, p1a);          \
    p0a = fmaf(shv[2], L0.z, p0a);  p1a = fmaf(shv[2], M0_.z, p1a);          \
    p0a = fmaf(shv[3], L0.w, p0a);  p1a = fmaf(shv[3], M0_.w, p1a);          \
    p0a = fmaf(shv[4], L1.x, p0a);  p1a = fmaf(shv[4], M1_.x, p1a);          \
    p0a = fmaf(shv[5], L1.y, p0a);  p1a = fmaf(shv[5], M1_.y, p1a);          \
    p0a = fmaf(shv[6], L1.z, p0a);  p1a = fmaf(shv[6], M1_.z, p1a);          \
    p0a = fmaf(shv[7], L1.w, p0a);  p1a = fmaf(shv[7], M1_.w, p1a);          \
    p0b = fmaf(shv[8], L2.x, p0b);  p1b = fmaf(shv[8], M2_.x, p1b);          \
    p0b = fmaf(shv[9], L2.y, p0b);  p1b = fmaf(shv[9], M2_.y, p1b);          \
    p0b = fmaf(shv[10], L2.z, p0b); p1b = fmaf(shv[10], M2_.z, p1b);         \
    p0b = fmaf(shv[11], L2.w, p0b); p1b = fmaf(shv[11], M2_.w, p1b);         \
    p0b = fmaf(shv[12], L3.x, p0b); p1b = fmaf(shv[12], M3_.x, p1b);         \
    p0b = fmaf(shv[13], L3.y, p0b); p1b = fmaf(shv[13], M3_.y, p1b);         \
    p0b = fmaf(shv[14], L3.z, p0b); p1b = fmaf(shv[14], M3_.z, p1b);         \
    p0b = fmaf(shv[15], L3.w, p0b); p1b = fmaf(shv[15], M3_.w, p1b);         \
    if (act) {                                                               \
      pool[RR][1024 + par * 800 + h * 100 + r0] = p0a + p0b;                 \
      pool[RR][1024 + par * 800 + h * 100 + r1] = p1a + p1b;                 \
    }                                                                        \
  }

#define FINALS(RR, M0, M1, L0V, L1V, SELV, ZV)                               \
  {                                                                          \
    const float* sp = pool[RR] + 1024 + par * 800;                           \
    float t00 = sp[0 * 100 + r0] + sp[1 * 100 + r0];                         \
    float t01 = sp[2 * 100 + r0] + sp[3 * 100 + r0];                         \
    float t02 = sp[4 * 100 + r0] + sp[5 * 100 + r0];                         \
    float t03 = sp[6 * 100 + r0] + sp[7 * 100 + r0];                         \
    float u00 = sp[0 * 100 + r1] + sp[1 * 100 + r1];                         \
    float u01 = sp[2 * 100 + r1] + sp[3 * 100 + r1];                         \
    float u02 = sp[4 * 100 + r1] + sp[5 * 100 + r1];                         \
    float u03 = sp[6 * 100 + r1] + sp[7 * 100 + r1];                         \
    float s0 = (t00 + t01) + (t02 + t03);                                    \
    float s1 = (u00 + u01) + (u02 + u03);                                    \
    L0V = (act && !(M0)) ? 10.0f * fast_tanh(s0) : NEG_INF;                  \
    L1V = (act && !(M1)) ? 10.0f * fast_tanh(s1) : NEG_INF;                  \
    float bv; int bi;                                                        \
    if (L1V > L0V) { bv = L1V; bi = r1; }                                    \
    else { bv = L0V; bi = act ? r0 : 1000; }                                 \
    float z = __expf(L0V) + __expf(L1V);                                     \
    {                                                                        \
      float cv; int ci; bool pr;                                             \
      cv = dppf<0xB1>(bv, -INFINITY); ci = dppi<0xB1>(bi, 0x7fffffff);       \
      z += dppf<0xB1>(z, 0.f);                                               \
      pr = (cv > bv) || (cv == bv && ci < bi); bv = pr ? cv : bv; bi = pr ? ci : bi; \
      cv = dppf<0x4E>(bv, -INFINITY); ci = dppi<0x4E>(bi, 0x7fffffff);       \
      z += dppf<0x4E>(z, 0.f);                                               \
      pr = (cv > bv) || (cv == bv && ci < bi); bv = pr ? cv : bv; bi = pr ? ci : bi; \
      cv = dppf<0x141>(bv, -INFINITY); ci = dppi<0x141>(bi, 0x7fffffff);     \
      z += dppf<0x141>(z, 0.f);                                              \
      pr = (cv > bv) || (cv == bv && ci < bi); bv = pr ? cv : bv; bi = pr ? ci : bi; \
      cv = dppf<0x140>(bv, -INFINITY); ci = dppi<0x140>(bi, 0x7fffffff);     \
      z += dppf<0x140>(z, 0.f);                                              \
      pr = (cv > bv) || (cv == bv && ci < bi); bv = pr ? cv : bv; bi = pr ? ci : bi; \
      cv = dppf<0x142>(bv, -INFINITY); ci = dppi<0x142>(bi, 0x7fffffff);     \
      z += dppf<0x142>(z, 0.f);                                              \
      pr = (cv > bv) || (cv == bv && ci < bi); bv = pr ? cv : bv; bi = pr ? ci : bi; \
      cv = dppf<0x143>(bv, -INFINITY); ci = dppi<0x143>(bi, 0x7fffffff);     \
      z += dppf<0x143>(z, 0.f);                                              \
      pr = (cv > bv) || (cv == bv && ci < bi); bv = pr ? cv : bv; bi = pr ? ci : bi; \
    }                                                                        \
    SELV = __builtin_amdgcn_readlane(bi, 63);                                \
    ZV = rdlane63f(z);                                                       \
  }

#define TFOLD(RR, BV, SELV)                                                  \
  {                                                                          \
    const float* erow = emb + (size_t)(BV)*12800 + (size_t)(SELV)*128;       \
    float fa = 0.f;                                                          \
    for (int i = 0; i < 32; ++i) {                                           \
      int e = qg * 32 + i;                                                   \
      fa = fmaf(erow[e], W_step[(size_t)e * 128 + h * 16 + dp], fa);         \
    }                                                                        \
    fa += dppf<0xB1>(fa, 0.f);                                               \
    fa += dppf<0x4E>(fa, 0.f);                                               \
    if ((l & 3) == 0) sbase[RR][h][l >> 2] += 0.25f * fa;                    \
  }

#pragma unroll 1
  for (int t = 0; t < 100; ++t) {
    float vA0, vA1, vB0, vB1;
    COMPAT(0, bA, lastA, m0A, m1A, vA0, vA1)
    COMPAT(1, bB, lastB, m0B, m1B, vB0, vB1)

    float eA0 = __expf(vA0), eA1 = __expf(vA1);
    float eB0 = __expf(vB0), eB1 = __expf(vB1);
    if (act) {
      float* sA = pool[0] + h * 112;
      float* sB = pool[1] + h * 112;
      sA[qq0 * 28 + ii0] = eA0;
      sA[(qq0 + 2) * 28 + ii0] = eA1;
      sB[qq0 * 28 + ii0] = eB0;
      sB[(qq0 + 2) * 28 + ii0] = eB1;
    }
    WSYNC();

    float sA = wred_sum(eA0 + eA1);
    float sB = wred_sum(eB0 + eB1);

    HEADS_LOGITS(0, bA, gvtA, sA, eA0, eA1)
    HEADS_LOGITS(1, bB, gvtB, sB, eB0, eB1)
    __syncthreads();  // THE barrier (both rows)

    float lA0, lA1, lB0, lB1, zA, zB;
    int selA, selB;
    FINALS(0, m0A, m1A, lA0, lA1, selA, zA)
    FINALS(1, m0B, m1B, lB0, lB1, selB, zB)

    if (h == 0) {
      float lsA = __logf(zA);
      float lsB = __logf(zB);
      if (l == 0) {
        out_pi[bA * 100 + t] = (float)selA;
        out_pi[bB * 100 + t] = (float)selB;
      }
      if (act) {
        out_logp[lpA + (size_t)t * 100 + r0] = lA0 - lsA;
        out_logp[lpA + (size_t)t * 100 + r1] = lA1 - lsA;
        out_logp[lpB + (size_t)t * 100 + r0] = lB0 - lsB;
        out_logp[lpB + (size_t)t * 100 + r1] = lB1 - lsB;
      }
    }

    if (t == 0) {
      TFOLD(0, bA, selA)
      TFOLD(1, bB, selB)
      WSYNC();
    }

    m0A = m0A || (act && selA == r0);
    m1A = m1A || (act && selA == r1);
    m0B = m0B || (act && selB == r0);
    m1B = m1B || (act && selB == r1);
    lastA = selA;
    lastB = selB;
    par ^= 1;
  }
#undef COMPAT
#undef HEADS_LOGITS
#undef FINALS
#undef TFOLD
}

extern "C" void kernel_launch(void* const* d_in, const int* in_sizes, int n_in,
                              void* d_out, int out_size, void* d_ws, size_t ws_size,
                              hipStream_t stream) {
  const float* emb     = (const float*)d_in[0];
  const float* W_node  = (const float*)d_in[1];
  const float* W_fixed = (const float*)d_in[2];
  const float* W_step  = (const float*)d_in[3];
  const float* W_out   = (const float*)d_in[4];
  const float* W_ph    = (const float*)d_in[5];
  float* ws  = (float*)d_ws;
  float* out = (float*)d_out;

  hipLaunchKernelGGL(pre_kernel, dim3(65), dim3(128), 0, stream,
                     W_node, W_out, W_step, W_ph, ws);

  float* Eg  = ws + 16512;
  float* Lkg = ws + 16512 + 26214400;   // 209.8 MB total (proven available R11)
  hipLaunchKernelGGL(ecomp_kernel, dim3(2048), dim3(512), 0, stream,
                     emb, W_step, Eg);
  hipLaunchKernelGGL(lcomp_kernel, dim3(2048), dim3(512), 0, stream,
                     emb, ws, Lkg);
  hipLaunchKernelGGL(decode_u, dim3(1024), dim3(512), 0, stream,
                     emb, W_node, W_fixed, W_step, ws, Eg, Lkg,
                     out, out + 20480000);
}

// Round 14
// 3089.064 us; speedup vs baseline: 1.0686x; 1.0686x over previous
//
#include <hip/hip_runtime.h>
#include <math.h>

#define NEG_INF (-1e9f)
#define WSYNC() asm volatile("s_waitcnt lgkmcnt(0)" ::: "memory")
#define SW(n) ((((n) ^ ((n) >> 3))) & 7)

template <int CTRL>
__device__ __forceinline__ float dppf(float x, float oldv) {
  return __int_as_float(__builtin_amdgcn_update_dpp(
      __float_as_int(oldv), __float_as_int(x), CTRL, 0xF, 0xF, false));
}
template <int CTRL>
__device__ __forceinline__ int dppi(int x, int oldv) {
  return __builtin_amdgcn_update_dpp(oldv, x, CTRL, 0xF, 0xF, false);
}
__device__ __forceinline__ float rdlane63f(float x) {
  return __int_as_float(__builtin_amdgcn_readlane(__float_as_int(x), 63));
}
__device__ __forceinline__ float wred_sum(float x) {
  x += dppf<0xB1>(x, 0.f);
  x += dppf<0x4E>(x, 0.f);
  x += dppf<0x141>(x, 0.f);
  x += dppf<0x140>(x, 0.f);
  x += dppf<0x142>(x, 0.f);
  x += dppf<0x143>(x, 0.f);
  return rdlane63f(x);
}
__device__ __forceinline__ float fast_tanh(float x) {
  float t = __expf(-2.0f * fabsf(x));
  float r = (1.0f - t) / (1.0f + t);
  return copysignf(r, x);
}

// ---------------------------------------------------------------------------
// pre_kernel: ws[0..16383] = Wc (1/sqrt(128) folded); ws[16384..16511] = qp
// ---------------------------------------------------------------------------
__global__ __launch_bounds__(128) void pre_kernel(
    const float* __restrict__ W_node, const float* __restrict__ W_out,
    const float* __restrict__ W_step, const float* __restrict__ W_ph,
    float* __restrict__ ws) {
  const int bi = blockIdx.x;
  const int tid = threadIdx.x;
  if (bi < 64) {
    __shared__ float woT[64][133];
    float acc0 = 0.f, acc1 = 0.f;
    const int e0 = bi * 2, e1 = e0 + 1;
    for (int ch = 0; ch < 2; ++ch) {
      const int j0 = ch * 64;
      for (int it = 0; it < 64; ++it) {
        int idx = tid + it * 128;
        int jj = idx & 63, ds = idx >> 6;
        woT[jj][ds] = W_out[ds * 128 + j0 + jj];
      }
      __syncthreads();
      for (int jj = 0; jj < 64; ++jj) {
        int j = j0 + jj;
        float a0 = W_node[e0 * 384 + 256 + j];
        float a1 = W_node[e1 * 384 + 256 + j];
        float bb = woT[jj][tid];
        acc0 = fmaf(a0, bb, acc0);
        acc1 = fmaf(a1, bb, acc1);
      }
      __syncthreads();
    }
    const float rs = 0.08838834764831845f;  // 1/sqrt(128)
    ws[e0 * 128 + tid] = acc0 * rs;
    ws[e1 * 128 + tid] = acc1 * rs;
  } else {
    float acc = 0.f;
    for (int i = 0; i < 256; ++i) acc = fmaf(W_ph[i], W_step[i * 128 + tid], acc);
    ws[16384 + tid] = acc;
  }
}

// ---------------------------------------------------------------------------
// ecomp_kernel: Eg[b][n][d] = 0.25 * sum_e emb[b][n][e] * W_step[128+e][d]
// ---------------------------------------------------------------------------
__global__ __launch_bounds__(512) void ecomp_kernel(
    const float* __restrict__ emb, const float* __restrict__ W_step,
    float* __restrict__ Eg) {
  const int b = blockIdx.x;
  const int tid = threadIdx.x;
  const int c = tid & 31;
  const int g = tid >> 5;

  __shared__ __align__(16) float semb[100 * 128];
  __shared__ __align__(16) float sW[128 * 128];

  float4* semb4 = (float4*)semb;
  float4* sW4 = (float4*)sW;
  const float4* embB4 = (const float4*)(emb + (size_t)b * 12800);
  const float4* Wb4 = (const float4*)(W_step + 128 * 128);

  for (int it = 0; it < 7; ++it) {
    int qi = tid + it * 512;
    if (qi < 3200) {
      int n = qi >> 5, cc = qi & 31;
      semb4[n * 32 + (cc ^ SW(n))] = embB4[qi];
    }
  }
  for (int it = 0; it < 8; ++it) sW4[tid + it * 512] = Wb4[tid + it * 512];
  __syncthreads();

  float4 acc[7];
#pragma unroll
  for (int k = 0; k < 7; ++k) acc[k] = make_float4(0.f, 0.f, 0.f, 0.f);
#pragma unroll 2
  for (int e4 = 0; e4 < 32; ++e4) {
    float4 em[7];
#pragma unroll
    for (int k = 0; k < 7; ++k) {
      int n = g + 16 * k; n = (n < 100) ? n : 99;
      em[k] = semb4[n * 32 + (e4 ^ SW(n))];
    }
#pragma unroll
    for (int eo = 0; eo < 4; ++eo) {
      float4 w4 = sW4[(e4 * 4 + eo) * 32 + c];
#pragma unroll
      for (int k = 0; k < 7; ++k) {
        const float ev = (eo == 0) ? em[k].x : (eo == 1) ? em[k].y
                       : (eo == 2) ? em[k].z : em[k].w;
        acc[k].x = fmaf(ev, w4.x, acc[k].x);
        acc[k].y = fmaf(ev, w4.y, acc[k].y);
        acc[k].z = fmaf(ev, w4.z, acc[k].z);
        acc[k].w = fmaf(ev, w4.w, acc[k].w);
      }
    }
  }
  float4* Eg4 = (float4*)Eg;
#pragma unroll
  for (int k = 0; k < 7; ++k) {
    int n = g + 16 * k;
    if (n < 100)
      Eg4[((size_t)b * 100 + n) * 32 + c] =
          make_float4(0.25f * acc[k].x, 0.25f * acc[k].y,
                      0.25f * acc[k].z, 0.25f * acc[k].w);
  }
}

// ---------------------------------------------------------------------------
// lcomp_kernel: Lk[b][n][d] = sum_e emb[b][n][e] * Wc[e][d]
// ---------------------------------------------------------------------------
__global__ __launch_bounds__(512) void lcomp_kernel(
    const float* __restrict__ emb, const float* __restrict__ Wc,
    float* __restrict__ Lk) {
  const int b = blockIdx.x;
  const int tid = threadIdx.x;
  const int c = tid & 31;
  const int g = tid >> 5;

  __shared__ __align__(16) float semb[100 * 128];
  __shared__ __align__(16) float sW[128 * 128];

  float4* semb4 = (float4*)semb;
  float4* sW4 = (float4*)sW;
  const float4* embB4 = (const float4*)(emb + (size_t)b * 12800);
  const float4* Wb4 = (const float4*)Wc;

  for (int it = 0; it < 7; ++it) {
    int qi = tid + it * 512;
    if (qi < 3200) {
      int n = qi >> 5, cc = qi & 31;
      semb4[n * 32 + (cc ^ SW(n))] = embB4[qi];
    }
  }
  for (int it = 0; it < 8; ++it) sW4[tid + it * 512] = Wb4[tid + it * 512];
  __syncthreads();

  float4 acc[7];
#pragma unroll
  for (int k = 0; k < 7; ++k) acc[k] = make_float4(0.f, 0.f, 0.f, 0.f);
#pragma unroll 2
  for (int e4 = 0; e4 < 32; ++e4) {
    float4 em[7];
#pragma unroll
    for (int k = 0; k < 7; ++k) {
      int n = g + 16 * k; n = (n < 100) ? n : 99;
      em[k] = semb4[n * 32 + (e4 ^ SW(n))];
    }
#pragma unroll
    for (int eo = 0; eo < 4; ++eo) {
      float4 w4 = sW4[(e4 * 4 + eo) * 32 + c];
#pragma unroll
      for (int k = 0; k < 7; ++k) {
        const float ev = (eo == 0) ? em[k].x : (eo == 1) ? em[k].y
                       : (eo == 2) ? em[k].z : em[k].w;
        acc[k].x = fmaf(ev, w4.x, acc[k].x);
        acc[k].y = fmaf(ev, w4.y, acc[k].y);
        acc[k].z = fmaf(ev, w4.z, acc[k].z);
        acc[k].w = fmaf(ev, w4.w, acc[k].w);
      }
    }
  }
  float4* Lk4 = (float4*)Lk;
#pragma unroll
  for (int k = 0; k < 7; ++k) {
    int n = g + 16 * k;
    if (n < 100) Lk4[((size_t)b * 100 + n) * 32 + c] = acc[k];
  }
}

// ---------------------------------------------------------------------------
// decode_w: dual-row, resources placed by R13's lessons:
//   gk -> REGISTERS (64; the hottest per-step operand; R13's LDS-gk caused the
//     LDS-issue wall), gvt -> LDS stride-25 scalar layout (conflict-free:
//     lane offsets 25*(4dp+qg), 25 odd -> 32 banks, 2 lanes/bank), lk' ->
//     global per-step (R11-proven), Eg -> prefetched right after sel
//     (R8-proven), E/F base read from LDS broadcast. No spill canary:
//     WRITE_SIZE must stay ~81 MB.
// ---------------------------------------------------------------------------
__global__ __launch_bounds__(512) void decode_w(
    const float* __restrict__ emb,      // [2048][100][128]
    const float* __restrict__ W_node,   // [128][384]
    const float* __restrict__ W_fixed,  // [128][128]
    const float* __restrict__ W_step,   // [256][128]
    const float* __restrict__ ws,       // Wc + qp
    const float* __restrict__ Eg,       // 0.25*E
    const float* __restrict__ Lkg,      // lk'
    float* __restrict__ out_logp,       // [2048][100][100]
    float* __restrict__ out_pi) {       // [2048][100]
  const int tid = threadIdx.x;
  const int h = tid >> 6;
  const int l = tid & 63;
  const int dp = l >> 2;
  const int qg = l & 3;
  const bool act = (l < 50);
  const int r0 = act ? l : 0;
  const int r1 = act ? l + 50 : 0;
  const int qq0 = (l < 25) ? 0 : 1;
  const int ii0 = l - qq0 * 25;
  const int bA = blockIdx.x * 2;
  const int bB = bA + 1;

  __shared__ float gvtL[2][12800];        // [rr][(h*16+j)*100 + n] 102,400 B
  __shared__ __align__(16) float pool[2][2752];  // attn 0..895 | spart 1024..2623 | sqp 2624..2751
  __shared__ __align__(16) float sbase[2][8][16];

  float gkA0[16], gkA1[16], gkB0[16], gkB1[16];

  // ======================= INIT (row-sequential) ==========================
#define INIT_ROW(RR, BV, GK0, GK1)                                           \
  {                                                                          \
    const float* embB = emb + (size_t)(BV)*12800;                            \
    const float4* embB4 = (const float4*)embB;                               \
    {                                                                        \
      int d = tid & 127, q2 = tid >> 7;                                      \
      float p = 0.f;                                                         \
      for (int n = q2 * 25; n < q2 * 25 + 25; ++n) p += embB[n * 128 + d];   \
      pool[RR][q2 * 128 + d] = p;                                            \
    }                                                                        \
    __syncthreads();                                                         \
    if (tid < 128)                                                           \
      pool[RR][512 + tid] = (pool[RR][tid] + pool[RR][128 + tid] +           \
                             pool[RR][256 + tid] + pool[RR][384 + tid]) * 0.01f; \
    __syncthreads();                                                         \
    {                                                                        \
      float a = 0.f;                                                         \
      for (int i = 0; i < 32; ++i) {                                         \
        int e = qg * 32 + i;                                                 \
        a = fmaf(pool[RR][512 + e], W_fixed[e * 128 + h * 16 + dp], a);      \
      }                                                                      \
      a += dppf<0xB1>(a, 0.f);                                               \
      a += dppf<0x4E>(a, 0.f);                                               \
      if ((l & 3) == 0) sbase[RR][h][l >> 2] = 0.25f * a;                    \
    }                                                                        \
    {                                                                        \
      float gv0[16], gv1[16];                                                \
      _Pragma("unroll")                                                      \
      for (int j = 0; j < 16; ++j) gv0[j] = gv1[j] = 0.f;                    \
      _Pragma("unroll 2")                                                    \
      for (int e4 = 0; e4 < 32; ++e4) {                                      \
        float4 a0 = embB4[r0 * 32 + e4];                                     \
        float4 a1 = embB4[r1 * 32 + e4];                                     \
        float em0[4] = {a0.x, a0.y, a0.z, a0.w};                             \
        float em1[4] = {a1.x, a1.y, a1.z, a1.w};                             \
        _Pragma("unroll")                                                    \
        for (int eo = 0; eo < 4; ++eo) {                                     \
          const int e = e4 * 4 + eo;                                         \
          const float ev0 = em0[eo], ev1 = em1[eo];                          \
          const float* wv = &W_node[e * 384 + 128 + h * 16];                 \
          _Pragma("unroll")                                                  \
          for (int j = 0; j < 16; ++j) {                                     \
            float wvj = wv[j];                                               \
            gv0[j] = fmaf(ev0, wvj, gv0[j]);                                 \
            gv1[j] = fmaf(ev1, wvj, gv1[j]);                                 \
          }                                                                  \
        }                                                                    \
      }                                                                      \
      if (act) {                                                             \
        _Pragma("unroll")                                                    \
        for (int j = 0; j < 16; ++j) {                                       \
          gvtL[RR][(h * 16 + j) * 100 + r0] = gv0[j];                        \
          gvtL[RR][(h * 16 + j) * 100 + r1] = gv1[j];                        \
        }                                                                    \
      }                                                                      \
    }                                                                        \
    {                                                                        \
      _Pragma("unroll")                                                      \
      for (int j = 0; j < 16; ++j) GK0[j] = GK1[j] = 0.f;                    \
      _Pragma("unroll 2")                                                    \
      for (int e4 = 0; e4 < 32; ++e4) {                                      \
        float4 a0 = embB4[r0 * 32 + e4];                                     \
        float4 a1 = embB4[r1 * 32 + e4];                                     \
        float em0[4] = {a0.x, a0.y, a0.z, a0.w};                             \
        float em1[4] = {a1.x, a1.y, a1.z, a1.w};                             \
        _Pragma("unroll")                                                    \
        for (int eo = 0; eo < 4; ++eo) {                                     \
          const int e = e4 * 4 + eo;                                         \
          const float ev0 = em0[eo], ev1 = em1[eo];                          \
          const float* wk = &W_node[e * 384 + h * 16];                       \
          _Pragma("unroll")                                                  \
          for (int j = 0; j < 16; ++j) {                                     \
            float wkj = wk[j];                                               \
            GK0[j] = fmaf(ev0, wkj, GK0[j]);                                 \
            GK1[j] = fmaf(ev1, wkj, GK1[j]);                                 \
          }                                                                  \
        }                                                                    \
      }                                                                      \
    }                                                                        \
    WSYNC();                                                                 \
    if (l == 0) {                                                            \
      _Pragma("unroll")                                                      \
      for (int j = 0; j < 16; ++j)                                           \
        pool[RR][2624 + h * 16 + j] =                                        \
            sbase[RR][h][j] + 0.25f * ws[16384 + h * 16 + j];                \
    }                                                                        \
  }

  INIT_ROW(0, bA, gkA0, gkA1)
  INIT_ROW(1, bB, gkB0, gkB1)
#undef INIT_ROW
  __syncthreads();  // gvtL / sqp / sbase visible block-wide

  // ======================= decode loop ====================================
  bool m0A = false, m1A = false, m0B = false, m1B = false;
  int par = 0;
  const size_t lpA = (size_t)bA * 10000;
  const size_t lpB = (size_t)bB * 10000;
  float4 gA0 = make_float4(0, 0, 0, 0), gA1 = gA0, gA2 = gA0, gA3 = gA0;
  float4 gB0 = gA0, gB1 = gA0, gB2 = gA0, gB3 = gA0;

#define COMPAT(RR, GK0, GK1, G0, G1, G2, G3, M0, M1, V0, V1)                 \
  {                                                                          \
    float q[16];                                                             \
    if (t == 0) {                                                            \
      const float4* qp = (const float4*)(pool[RR] + 2624 + h * 16);          \
      _Pragma("unroll")                                                      \
      for (int jj = 0; jj < 4; ++jj) {                                       \
        float4 v = qp[jj];                                                   \
        q[4 * jj + 0] = v.x; q[4 * jj + 1] = v.y;                            \
        q[4 * jj + 2] = v.z; q[4 * jj + 3] = v.w;                            \
      }                                                                      \
    } else {                                                                 \
      const float4* sb = (const float4*)&sbase[RR][h][0];                    \
      float4 c0 = sb[0], c1 = sb[1], c2 = sb[2], c3 = sb[3];                 \
      q[0] = c0.x + (G0).x; q[1] = c0.y + (G0).y;                            \
      q[2] = c0.z + (G0).z; q[3] = c0.w + (G0).w;                            \
      q[4] = c1.x + (G1).x; q[5] = c1.y + (G1).y;                            \
      q[6] = c1.z + (G1).z; q[7] = c1.w + (G1).w;                            \
      q[8] = c2.x + (G2).x;  q[9] = c2.y + (G2).y;                           \
      q[10] = c2.z + (G2).z; q[11] = c2.w + (G2).w;                          \
      q[12] = c3.x + (G3).x; q[13] = c3.y + (G3).y;                          \
      q[14] = c3.z + (G3).z; q[15] = c3.w + (G3).w;                          \
    }                                                                        \
    float c0a = 0.f, c0b = 0.f, c1a = 0.f, c1b = 0.f;                        \
    _Pragma("unroll")                                                        \
    for (int j = 0; j < 8; ++j) {                                            \
      c0a = fmaf(q[j], GK0[j], c0a);                                         \
      c1a = fmaf(q[j], GK1[j], c1a);                                         \
    }                                                                        \
    _Pragma("unroll")                                                        \
    for (int j = 8; j < 16; ++j) {                                           \
      c0b = fmaf(q[j], GK0[j], c0b);                                         \
      c1b = fmaf(q[j], GK1[j], c1b);                                         \
    }                                                                        \
    V0 = (act && !(M0)) ? (c0a + c0b) : NEG_INF;                             \
    V1 = (act && !(M1)) ? (c1a + c1b) : NEG_INF;                             \
  }

#define HEADS_LOGITS(RR, BV, SV)                                             \
  {                                                                          \
    const float* ap = pool[RR] + h * 112 + qg * 28;                          \
    const float* gp = &gvtL[RR][(h * 16 + dp) * 100 + qg * 25];              \
    float ha = 0.f, hb = 0.f;                                                \
    _Pragma("unroll")                                                        \
    for (int ii = 0; ii < 6; ++ii) {                                         \
      float4 v = ((const float4*)ap)[ii];                                    \
      ha = fmaf(v.x, gp[4 * ii + 0], ha);                                    \
      hb = fmaf(v.y, gp[4 * ii + 1], hb);                                    \
      ha = fmaf(v.z, gp[4 * ii + 2], ha);                                    \
      hb = fmaf(v.w, gp[4 * ii + 3], hb);                                    \
    }                                                                        \
    ha = fmaf(ap[24], gp[24], ha);                                           \
    float hacc = ha + hb;                                                    \
    hacc += dppf<0xB1>(hacc, 0.f);                                           \
    hacc += dppf<0x4E>(hacc, 0.f);                                           \
    float hd = hacc / (SV);                                                  \
    float shv[16];                                                           \
    _Pragma("unroll")                                                        \
    for (int j = 0; j < 16; ++j)                                             \
      shv[j] = __int_as_float(                                               \
          __builtin_amdgcn_readlane(__float_as_int(hd), 4 * j));             \
    const float4* lkp0 =                                                     \
        (const float4*)(Lkg + ((size_t)(BV)*100 + r0) * 128 + h * 16);       \
    const float4* lkp1 =                                                     \
        (const float4*)(Lkg + ((size_t)(BV)*100 + r1) * 128 + h * 16);       \
    float4 L0 = lkp0[0], L1 = lkp0[1], L2 = lkp0[2], L3 = lkp0[3];           \
    float4 N0 = lkp1[0], N1 = lkp1[1], N2 = lkp1[2], N3 = lkp1[3];           \
    float p0a = 0.f, p0b = 0.f, p1a = 0.f, p1b = 0.f;                        \
    p0a = fmaf(shv[0], L0.x, p0a);  p1a = fmaf(shv[0], N0.x, p1a);           \
    p0a = fmaf(shv[1], L0.y, p0a);  p1a = fmaf(shv[1], N0.y, p1a);           \
    p0a = fmaf(shv[2], L0.z, p0a);  p1a = fmaf(shv[2], N0.z, p1a);           \
    p0a = fmaf(shv[3], L0.w, p0a);  p1a = fmaf(shv[3], N0.w, p1a);           \
    p0a = fmaf(shv[4], L1.x, p0a);  p1a = fmaf(shv[4], N1.x, p1a);           \
    p0a = fmaf(shv[5], L1.y, p0a);  p1a = fmaf(shv[5], N1.y, p1a);           \
    p0a = fmaf(shv[6], L1.z, p0a);  p1a = fmaf(shv[6], N1.z, p1a);           \
    p0a = fmaf(shv[7], L1.w, p0a);  p1a = fmaf(shv[7], N1.w, p1a);           \
    p0b = fmaf(shv[8], L2.x, p0b);  p1b = fmaf(shv[8], N2.x, p1b);           \
    p0b = fmaf(shv[9], L2.y, p0b);  p1b = fmaf(shv[9], N2.y, p1b);           \
    p0b = fmaf(shv[10], L2.z, p0b); p1b = fmaf(shv[10], N2.z, p1b);          \
    p0b = fmaf(shv[11], L2.w, p0b); p1b = fmaf(shv[11], N2.w, p1b);          \
    p0b = fmaf(shv[12], L3.x, p0b); p1b = fmaf(shv[12], N3.x, p1b);          \
    p0b = fmaf(shv[13], L3.y, p0b); p1b = fmaf(shv[13], N3.y, p1b);          \
    p0b = fmaf(shv[14], L3.z, p0b); p1b = fmaf(shv[14], N3.z, p1b);          \
    p0b = fmaf(shv[15], L3.w, p0b); p1b = fmaf(shv[15], N3.w, p1b);          \
    if (act) {                                                               \
      pool[RR][1024 + par * 800 + h * 100 + r0] = p0a + p0b;                 \
      pool[RR][1024 + par * 800 + h * 100 + r1] = p1a + p1b;                 \
    }                                                                        \
  }

#define FINALS(RR, M0, M1, L0V, L1V, SELV, ZV)                               \
  {                                                                          \
    const float* sp = pool[RR] + 1024 + par * 800;                           \
    float t00 = sp[0 * 100 + r0] + sp[1 * 100 + r0];                         \
    float t01 = sp[2 * 100 + r0] + sp[3 * 100 + r0];                         \
    float t02 = sp[4 * 100 + r0] + sp[5 * 100 + r0];                         \
    float t03 = sp[6 * 100 + r0] + sp[7 * 100 + r0];                         \
    float u00 = sp[0 * 100 + r1] + sp[1 * 100 + r1];                         \
    float u01 = sp[2 * 100 + r1] + sp[3 * 100 + r1];                         \
    float u02 = sp[4 * 100 + r1] + sp[5 * 100 + r1];                         \
    float u03 = sp[6 * 100 + r1] + sp[7 * 100 + r1];                         \
    float s0 = (t00 + t01) + (t02 + t03);                                    \
    float s1 = (u00 + u01) + (u02 + u03);                                    \
    L0V = (act && !(M0)) ? 10.0f * fast_tanh(s0) : NEG_INF;                  \
    L1V = (act && !(M1)) ? 10.0f * fast_tanh(s1) : NEG_INF;                  \
    float bv; int bi;                                                        \
    if (L1V > L0V) { bv = L1V; bi = r1; }                                    \
    else { bv = L0V; bi = act ? r0 : 1000; }                                 \
    float z = __expf(L0V) + __expf(L1V);                                     \
    {                                                                        \
      float cv; int ci; bool pr;                                             \
      cv = dppf<0xB1>(bv, -INFINITY); ci = dppi<0xB1>(bi, 0x7fffffff);       \
      z += dppf<0xB1>(z, 0.f);                                               \
      pr = (cv > bv) || (cv == bv && ci < bi); bv = pr ? cv : bv; bi = pr ? ci : bi; \
      cv = dppf<0x4E>(bv, -INFINITY); ci = dppi<0x4E>(bi, 0x7fffffff);       \
      z += dppf<0x4E>(z, 0.f);                                               \
      pr = (cv > bv) || (cv == bv && ci < bi); bv = pr ? cv : bv; bi = pr ? ci : bi; \
      cv = dppf<0x141>(bv, -INFINITY); ci = dppi<0x141>(bi, 0x7fffffff);     \
      z += dppf<0x141>(z, 0.f);                                              \
      pr = (cv > bv) || (cv == bv && ci < bi); bv = pr ? cv : bv; bi = pr ? ci : bi; \
      cv = dppf<0x140>(bv, -INFINITY); ci = dppi<0x140>(bi, 0x7fffffff);     \
      z += dppf<0x140>(z, 0.f);                                              \
      pr = (cv > bv) || (cv == bv && ci < bi); bv = pr ? cv : bv; bi = pr ? ci : bi; \
      cv = dppf<0x142>(bv, -INFINITY); ci = dppi<0x142>(bi, 0x7fffffff);     \
      z += dppf<0x142>(z, 0.f);                                              \
      pr = (cv > bv) || (cv == bv && ci < bi); bv = pr ? cv : bv; bi = pr ? ci : bi; \
      cv = dppf<0x143>(bv, -INFINITY); ci = dppi<0x143>(bi, 0x7fffffff);     \
      z += dppf<0x143>(z, 0.f);                                              \
      pr = (cv > bv) || (cv == bv && ci < bi); bv = pr ? cv : bv; bi = pr ? ci : bi; \
    }                                                                        \
    SELV = __builtin_amdgcn_readlane(bi, 63);                                \
    ZV = rdlane63f(z);                                                       \
  }

#define TFOLD(RR, BV, SELV)                                                  \
  {                                                                          \
    const float* erow = emb + (size_t)(BV)*12800 + (size_t)(SELV)*128;       \
    float fa = 0.f;                                                          \
    for (int i = 0; i < 32; ++i) {                                           \
      int e = qg * 32 + i;                                                   \
      fa = fmaf(erow[e], W_step[(size_t)e * 128 + h * 16 + dp], fa);         \
    }                                                                        \
    fa += dppf<0xB1>(fa, 0.f);                                               \
    fa += dppf<0x4E>(fa, 0.f);                                               \
    if ((l & 3) == 0) sbase[RR][h][l >> 2] += 0.25f * fa;                    \
  }

#pragma unroll 1
  for (int t = 0; t < 100; ++t) {
    float vA0, vA1, vB0, vB1;
    COMPAT(0, gkA0, gkA1, gA0, gA1, gA2, gA3, m0A, m1A, vA0, vA1)
    COMPAT(1, gkB0, gkB1, gB0, gB1, gB2, gB3, m0B, m1B, vB0, vB1)

    float eA0 = __expf(vA0), eA1 = __expf(vA1);
    float eB0 = __expf(vB0), eB1 = __expf(vB1);
    if (act) {
      float* sA = pool[0] + h * 112;
      float* sB = pool[1] + h * 112;
      sA[qq0 * 28 + ii0] = eA0;
      sA[(qq0 + 2) * 28 + ii0] = eA1;
      sB[qq0 * 28 + ii0] = eB0;
      sB[(qq0 + 2) * 28 + ii0] = eB1;
    }
    WSYNC();

    float sA = wred_sum(eA0 + eA1);
    float sB = wred_sum(eB0 + eB1);

    HEADS_LOGITS(0, bA, sA)
    HEADS_LOGITS(1, bB, sB)
    __syncthreads();  // THE barrier (both rows)

    float lA0, lA1, lB0, lB1, zA, zB;
    int selA, selB;
    FINALS(0, m0A, m1A, lA0, lA1, selA, zA)
    FINALS(1, m0B, m1B, lB0, lB1, selB, zB)

    // Eg prefetch (R8 position: right after sel, hides L2/L3 latency under
    // outputs + t0 + next step's other-row work)
    {
      const float4* ea = (const float4*)(Eg + ((size_t)bA * 100 + selA) * 128 + h * 16);
      const float4* eb = (const float4*)(Eg + ((size_t)bB * 100 + selB) * 128 + h * 16);
      gA0 = ea[0]; gA1 = ea[1]; gA2 = ea[2]; gA3 = ea[3];
      gB0 = eb[0]; gB1 = eb[1]; gB2 = eb[2]; gB3 = eb[3];
    }

    if (h == 0) {
      float lsA = __logf(zA);
      float lsB = __logf(zB);
      if (l == 0) {
        out_pi[bA * 100 + t] = (float)selA;
        out_pi[bB * 100 + t] = (float)selB;
      }
      if (act) {
        out_logp[lpA + (size_t)t * 100 + r0] = lA0 - lsA;
        out_logp[lpA + (size_t)t * 100 + r1] = lA1 - lsA;
        out_logp[lpB + (size_t)t * 100 + r0] = lB0 - lsB;
        out_logp[lpB + (size_t)t * 100 + r1] = lB1 - lsB;
      }
    }

    if (t == 0) {
      TFOLD(0, bA, selA)
      TFOLD(1, bB, selB)
      WSYNC();
    }

    m0A = m0A || (act && selA == r0);
    m1A = m1A || (act && selA == r1);
    m0B = m0B || (act && selB == r0);
    m1B = m1B || (act && selB == r1);
    par ^= 1;
  }
#undef COMPAT
#undef HEADS_LOGITS
#undef FINALS
#undef TFOLD
}

extern "C" void kernel_launch(void* const* d_in, const int* in_sizes, int n_in,
                              void* d_out, int out_size, void* d_ws, size_t ws_size,
                              hipStream_t stream) {
  const float* emb     = (const float*)d_in[0];
  const float* W_node  = (const float*)d_in[1];
  const float* W_fixed = (const float*)d_in[2];
  const float* W_step  = (const float*)d_in[3];
  const float* W_out   = (const float*)d_in[4];
  const float* W_ph    = (const float*)d_in[5];
  float* ws  = (float*)d_ws;
  float* out = (float*)d_out;

  hipLaunchKernelGGL(pre_kernel, dim3(65), dim3(128), 0, stream,
                     W_node, W_out, W_step, W_ph, ws);

  float* Eg  = ws + 16512;
  float* Lkg = ws + 16512 + 26214400;   // 209.8 MB total (available, R11-13)
  hipLaunchKernelGGL(ecomp_kernel, dim3(2048), dim3(512), 0, stream,
                     emb, W_step, Eg);
  hipLaunchKernelGGL(lcomp_kernel, dim3(2048), dim3(512), 0, stream,
                     emb, ws, Lkg);
  hipLaunchKernelGGL(decode_w, dim3(1024), dim3(512), 0, stream,
                     emb, W_node, W_fixed, W_step, ws, Eg, Lkg,
                     out, out + 20480000);
}